// Round 1
// baseline (850.494 us; speedup 1.0000x reference)
//
#include <hip/hip_runtime.h>
#include <hip/hip_bf16.h>
#include <math.h>

#define N_NODES 50000
#define N_EDGES 800000
#define ET_EDGES (N_EDGES + N_NODES)
#define G_GROUPS 64
#define NEG_SLOPE 0.2f

// ---------------- CSR build ----------------

__global__ void count_edges(const int* __restrict__ ei, int* __restrict__ deg) {
    int e = blockIdx.x * blockDim.x + threadIdx.x;
    if (e >= ET_EDGES) return;
    int dst = (e < N_EDGES) ? ei[N_EDGES + e] : (e - N_EDGES);
    atomicAdd(&deg[dst], 1);
}

__global__ void scan_block(const int* __restrict__ deg, int* __restrict__ rowptr,
                           int* __restrict__ bsums, int n) {
    __shared__ int sd[256];
    int i = blockIdx.x * 256 + threadIdx.x;
    int v = (i < n) ? deg[i] : 0;
    sd[threadIdx.x] = v;
    __syncthreads();
    for (int off = 1; off < 256; off <<= 1) {
        int t = (threadIdx.x >= off) ? sd[threadIdx.x - off] : 0;
        __syncthreads();
        sd[threadIdx.x] += t;
        __syncthreads();
    }
    if (i < n) rowptr[i] = sd[threadIdx.x] - v;  // exclusive within block
    if (threadIdx.x == 255) bsums[blockIdx.x] = sd[255];
}

__global__ void scan_bsums(int* __restrict__ bsums, int nb) {
    __shared__ int sd[256];
    int v = (threadIdx.x < nb) ? bsums[threadIdx.x] : 0;
    sd[threadIdx.x] = v;
    __syncthreads();
    for (int off = 1; off < 256; off <<= 1) {
        int t = (threadIdx.x >= off) ? sd[threadIdx.x - off] : 0;
        __syncthreads();
        sd[threadIdx.x] += t;
        __syncthreads();
    }
    if (threadIdx.x < nb) bsums[threadIdx.x] = sd[threadIdx.x] - v;  // exclusive
}

__global__ void scan_add(int* __restrict__ rowptr, const int* __restrict__ bsums, int n) {
    int i = blockIdx.x * 256 + threadIdx.x;
    if (i < n) rowptr[i] += bsums[blockIdx.x];
    if (i == 0) rowptr[n] = ET_EDGES;
}

__global__ void fill_edges(const int* __restrict__ ei, const int* __restrict__ rowptr,
                           int* __restrict__ cursor, int* __restrict__ col) {
    int e = blockIdx.x * blockDim.x + threadIdx.x;
    if (e >= ET_EDGES) return;
    int src, dst;
    if (e < N_EDGES) { src = ei[e]; dst = ei[N_EDGES + e]; }
    else             { src = e - N_EDGES; dst = src; }
    int pos = rowptr[dst] + atomicAdd(&cursor[dst], 1);
    col[pos] = src;
}

// ---------------- GEMM: Y[N,128] = X[N,128] @ W[128,128] (+bias) ----------------

#define TILE_ROWS 32

__global__ __launch_bounds__(256) void gemm128(const float* __restrict__ X,
                                               const float* __restrict__ W,
                                               const float* __restrict__ bias,
                                               float* __restrict__ Y, int n, int addBias) {
    __shared__ float Wl[128 * 128];
    __shared__ float Xl[TILE_ROWS * 128];
    int t = threadIdx.x;
    for (int i = t * 4; i < 128 * 128; i += 1024)
        *(float4*)&Wl[i] = *(const float4*)&W[i];
    int row0 = blockIdx.x * TILE_ROWS;
    for (int i = t * 4; i < TILE_ROWS * 128; i += 1024) {
        int r = i >> 7, c = i & 127;
        int gr = row0 + r;
        float4 v = make_float4(0.f, 0.f, 0.f, 0.f);
        if (gr < n) v = *(const float4*)&X[(size_t)gr * 128 + c];
        *(float4*)&Xl[i] = v;
    }
    __syncthreads();
    int c = t & 127;
    int rbase = (t >> 7) * 16;
    float acc[16];
#pragma unroll
    for (int i = 0; i < 16; i++) acc[i] = 0.f;
    for (int k = 0; k < 128; k += 4) {
        float w0 = Wl[(k + 0) * 128 + c];
        float w1 = Wl[(k + 1) * 128 + c];
        float w2 = Wl[(k + 2) * 128 + c];
        float w3 = Wl[(k + 3) * 128 + c];
#pragma unroll
        for (int i = 0; i < 16; i++) {
            float4 xv = *(float4*)&Xl[(rbase + i) * 128 + k];
            float a = acc[i];
            a = fmaf(xv.x, w0, a);
            a = fmaf(xv.y, w1, a);
            a = fmaf(xv.z, w2, a);
            a = fmaf(xv.w, w3, a);
            acc[i] = a;
        }
    }
    float b = addBias ? bias[c] : 0.f;
#pragma unroll
    for (int i = 0; i < 16; i++) {
        int gr = row0 + rbase + i;
        if (gr < n) Y[(size_t)gr * 128 + c] = acc[i] + b;
    }
}

// ---------------- attention coefficients ----------------

template <int H>
__global__ void attn_coef(const float* __restrict__ hfeat, const float* __restrict__ asrc,
                          const float* __restrict__ adst, float* __restrict__ als,
                          float* __restrict__ ald, int n) {
    int idx = blockIdx.x * blockDim.x + threadIdx.x;
    if (idx >= n * H) return;
    int node = idx / H, h = idx % H;
    const int C = 128 / H;
    const float* hp = hfeat + (size_t)node * 128 + h * C;
    const float* ap = asrc + h * C;
    const float* dp = adst + h * C;
    float s = 0.f, d = 0.f;
#pragma unroll 8
    for (int c = 0; c < C; c++) {
        float v = hp[c];
        s = fmaf(v, ap[c], s);
        d = fmaf(v, dp[c], d);
    }
    als[idx] = s;
    ald[idx] = d;
}

// ---------------- aggregate (one wave per dst node) ----------------
// MODE 0: out = relu(agg + bias + xskip)   (layers 1,2)
// MODE 1: out = agg + bias                 (layer 3)

template <int H, int MODE>
__global__ __launch_bounds__(256) void aggregate(const float* __restrict__ hfeat,
                                                 const float* __restrict__ als,
                                                 const float* __restrict__ ald,
                                                 const int* __restrict__ rowptr,
                                                 const int* __restrict__ col,
                                                 const float* __restrict__ bias,
                                                 const float* __restrict__ xskip,
                                                 float* __restrict__ outbuf, int n) {
    int wave = (blockIdx.x * blockDim.x + threadIdx.x) >> 6;
    int lane = threadIdx.x & 63;
    if (wave >= n) return;
    int d = wave;
    int h = (H == 4) ? (lane >> 4) : 0;
    float aldh = ald[d * H + h];
    int beg = rowptr[d], end = rowptr[d + 1];

    float m = -3.4e38f;
    for (int i = beg; i < end; i++) {
        int s = col[i];
        float v = als[s * H + h] + aldh;
        v = (v > 0.f) ? v : NEG_SLOPE * v;
        m = fmaxf(m, v);
    }
    float ssum = 0.f, a0 = 0.f, a1 = 0.f;
    int c0 = 2 * lane;
    for (int i = beg; i < end; i++) {
        int s = col[i];
        float v = als[s * H + h] + aldh;
        v = (v > 0.f) ? v : NEG_SLOPE * v;
        float p = __expf(v - m);
        ssum += p;
        float2 hv = *(const float2*)&hfeat[(size_t)s * 128 + c0];
        a0 = fmaf(p, hv.x, a0);
        a1 = fmaf(p, hv.y, a1);
    }
    float inv = 1.f / ssum;
    float o0 = a0 * inv + bias[c0];
    float o1 = a1 * inv + bias[c0 + 1];
    if (MODE == 0) {
        o0 = fmaxf(o0 + xskip[(size_t)d * 128 + c0], 0.f);
        o1 = fmaxf(o1 + xskip[(size_t)d * 128 + c0 + 1], 0.f);
    }
    outbuf[(size_t)d * 128 + c0] = o0;
    outbuf[(size_t)d * 128 + c0 + 1] = o1;
}

// ---------------- pooling ----------------

__global__ void pool_sum(const float* __restrict__ h, const int* __restrict__ batch,
                         float* __restrict__ ctx, float* __restrict__ cnt, int n) {
    int c = threadIdx.x;  // 0..127
    int base = blockIdx.x * 128;
    int lim = min(base + 128, n);
    float acc = 0.f, cl = 0.f;
    int curg = -1;
    for (int node = base; node < lim; node++) {
        int g = batch[node];
        if (g != curg) {
            if (curg >= 0) {
                atomicAdd(&ctx[curg * 128 + c], acc);
                if (c == 0) atomicAdd(&cnt[curg], cl);
            }
            curg = g; acc = 0.f; cl = 0.f;
        }
        acc += h[(size_t)node * 128 + c];
        cl += 1.f;
    }
    if (curg >= 0) {
        atomicAdd(&ctx[curg * 128 + c], acc);
        if (c == 0) atomicAdd(&cnt[curg], cl);
    }
}

__global__ void pool_div(float* __restrict__ ctx, const float* __restrict__ cnt) {
    int i = blockIdx.x * blockDim.x + threadIdx.x;
    if (i >= G_GROUPS * 128) return;
    int g = i >> 7;
    ctx[i] = ctx[i] / fmaxf(cnt[g], 1.f);
}

// ---------------- host ----------------

extern "C" void kernel_launch(void* const* d_in, const int* in_sizes, int n_in,
                              void* d_out, int out_size, void* d_ws, size_t ws_size,
                              hipStream_t stream) {
    const float* x   = (const float*)d_in[0];
    const int*   ei  = (const int*)d_in[1];
    const int*   bat = (const int*)d_in[2];
    const float* Wp  = (const float*)d_in[3];
    const float* bp  = (const float*)d_in[4];
    const float* W1  = (const float*)d_in[5];
    const float* as1 = (const float*)d_in[6];
    const float* ad1 = (const float*)d_in[7];
    const float* b1  = (const float*)d_in[8];
    const float* W2  = (const float*)d_in[9];
    const float* as2 = (const float*)d_in[10];
    const float* ad2 = (const float*)d_in[11];
    const float* b2  = (const float*)d_in[12];
    const float* W3  = (const float*)d_in[13];
    const float* as3 = (const float*)d_in[14];
    const float* ad3 = (const float*)d_in[15];
    const float* b3  = (const float*)d_in[16];

    float* out_h   = (float*)d_out;
    float* out_ctx = out_h + (size_t)N_NODES * 128;

    char* w = (char*)d_ws;
    float* xskip = (float*)w;  w += (size_t)N_NODES * 128 * 4;
    float* hfeat = (float*)w;  w += (size_t)N_NODES * 128 * 4;
    float* hcur  = (float*)w;  w += (size_t)N_NODES * 128 * 4;
    float* als   = (float*)w;  w += (size_t)N_NODES * 4 * 4;
    float* ald   = (float*)w;  w += (size_t)N_NODES * 4 * 4;
    float* cnt   = (float*)w;  w += 256 * 4;
    int* deg     = (int*)w;    w += (size_t)N_NODES * 4;
    int* rowptr  = (int*)w;    w += (size_t)(N_NODES + 4) * 4;
    int* cursor  = (int*)w;    w += (size_t)N_NODES * 4;
    int* bsums   = (int*)w;    w += 256 * 4;
    int* col     = (int*)w;    w += (size_t)ET_EDGES * 4;

    // zero accumulators
    hipMemsetAsync(deg, 0, N_NODES * 4, stream);
    hipMemsetAsync(cursor, 0, N_NODES * 4, stream);
    hipMemsetAsync(cnt, 0, 256 * 4, stream);
    hipMemsetAsync(out_ctx, 0, G_GROUPS * 128 * 4, stream);

    const int NB = (N_NODES + 255) / 256;  // 196
    const int EB = (ET_EDGES + 255) / 256;

    // CSR build
    count_edges<<<EB, 256, 0, stream>>>(ei, deg);
    scan_block<<<NB, 256, 0, stream>>>(deg, rowptr, bsums, N_NODES);
    scan_bsums<<<1, 256, 0, stream>>>(bsums, NB);
    scan_add<<<NB, 256, 0, stream>>>(rowptr, bsums, N_NODES);
    fill_edges<<<EB, 256, 0, stream>>>(ei, rowptr, cursor, col);

    const int GB = (N_NODES + TILE_ROWS - 1) / TILE_ROWS;
    const int AB4 = (N_NODES * 4 + 255) / 256;
    const int AB1 = (N_NODES + 255) / 256;
    const int AGB = (N_NODES * 64 + 255) / 256;

    // x_skip = x @ Wp + bp
    gemm128<<<GB, 256, 0, stream>>>(x, Wp, bp, xskip, N_NODES, 1);

    // layer 1
    gemm128<<<GB, 256, 0, stream>>>(x, W1, nullptr, hfeat, N_NODES, 0);
    attn_coef<4><<<AB4, 256, 0, stream>>>(hfeat, as1, ad1, als, ald, N_NODES);
    aggregate<4, 0><<<AGB, 256, 0, stream>>>(hfeat, als, ald, rowptr, col, b1, xskip, hcur, N_NODES);

    // layer 2
    gemm128<<<GB, 256, 0, stream>>>(hcur, W2, nullptr, hfeat, N_NODES, 0);
    attn_coef<4><<<AB4, 256, 0, stream>>>(hfeat, as2, ad2, als, ald, N_NODES);
    aggregate<4, 0><<<AGB, 256, 0, stream>>>(hfeat, als, ald, rowptr, col, b2, xskip, hcur, N_NODES);

    // layer 3 (heads=1, no skip/relu) -> d_out
    gemm128<<<GB, 256, 0, stream>>>(hcur, W3, nullptr, hfeat, N_NODES, 0);
    attn_coef<1><<<AB1, 256, 0, stream>>>(hfeat, as3, ad3, als, ald, N_NODES);
    aggregate<1, 1><<<AGB, 256, 0, stream>>>(hfeat, als, ald, rowptr, col, b3, nullptr, out_h, N_NODES);

    // global mean pool
    pool_sum<<<(N_NODES + 127) / 128, 128, 0, stream>>>(out_h, bat, out_ctx, cnt, N_NODES);
    pool_div<<<(G_GROUPS * 128 + 255) / 256, 256, 0, stream>>>(out_ctx, cnt);
}

// Round 2
// 598.405 us; speedup vs baseline: 1.4213x; 1.4213x over previous
//
#include <hip/hip_runtime.h>
#include <hip/hip_bf16.h>
#include <math.h>

#define N_NODES 50000
#define N_EDGES 800000
#define ET_EDGES (N_EDGES + N_NODES)
#define G_GROUPS 64
#define NEG_SLOPE 0.2f

static __device__ __forceinline__ float bf16_lo(unsigned int u) {
    return __uint_as_float(u << 16);
}
static __device__ __forceinline__ float bf16_hi(unsigned int u) {
    return __uint_as_float(u & 0xffff0000u);
}
static __device__ __forceinline__ unsigned short f_to_bf16(float f) {
    unsigned int u = __float_as_uint(f);
    unsigned int r = (u + 0x7fffu + ((u >> 16) & 1u)) >> 16;  // RNE
    return (unsigned short)r;
}

// ---------------- CSR build ----------------

__global__ void count_edges(const int* __restrict__ ei, int* __restrict__ deg) {
    int e = blockIdx.x * blockDim.x + threadIdx.x;
    if (e >= ET_EDGES) return;
    int dst = (e < N_EDGES) ? ei[N_EDGES + e] : (e - N_EDGES);
    atomicAdd(&deg[dst], 1);
}

__global__ void scan_block(const int* __restrict__ deg, int* __restrict__ rowptr,
                           int* __restrict__ bsums, int n) {
    __shared__ int sd[256];
    int i = blockIdx.x * 256 + threadIdx.x;
    int v = (i < n) ? deg[i] : 0;
    sd[threadIdx.x] = v;
    __syncthreads();
    for (int off = 1; off < 256; off <<= 1) {
        int t = (threadIdx.x >= off) ? sd[threadIdx.x - off] : 0;
        __syncthreads();
        sd[threadIdx.x] += t;
        __syncthreads();
    }
    if (i < n) rowptr[i] = sd[threadIdx.x] - v;  // exclusive within block
    if (threadIdx.x == 255) bsums[blockIdx.x] = sd[255];
}

__global__ void scan_bsums(int* __restrict__ bsums, int nb) {
    __shared__ int sd[256];
    int v = (threadIdx.x < nb) ? bsums[threadIdx.x] : 0;
    sd[threadIdx.x] = v;
    __syncthreads();
    for (int off = 1; off < 256; off <<= 1) {
        int t = (threadIdx.x >= off) ? sd[threadIdx.x - off] : 0;
        __syncthreads();
        sd[threadIdx.x] += t;
        __syncthreads();
    }
    if (threadIdx.x < nb) bsums[threadIdx.x] = sd[threadIdx.x] - v;  // exclusive
}

__global__ void scan_add(int* __restrict__ rowptr, const int* __restrict__ bsums, int n) {
    int i = blockIdx.x * 256 + threadIdx.x;
    if (i < n) rowptr[i] += bsums[blockIdx.x];
    if (i == 0) rowptr[n] = ET_EDGES;
}

__global__ void fill_edges(const int* __restrict__ ei, const int* __restrict__ rowptr,
                           int* __restrict__ cursor, int* __restrict__ col) {
    int e = blockIdx.x * blockDim.x + threadIdx.x;
    if (e >= ET_EDGES) return;
    int src, dst;
    if (e < N_EDGES) { src = ei[e]; dst = ei[N_EDGES + e]; }
    else             { src = e - N_EDGES; dst = src; }
    int pos = rowptr[dst] + atomicAdd(&cursor[dst], 1);
    col[pos] = src;
}

// ---------------- GEMM: Y[N,128] = X[N,128] @ W[128,128] (+bias) ----------------
// BF16OUT: write bf16 (hfeat); else fp32 (xskip).

#define TILE_ROWS 32

template <int BF16OUT>
__global__ __launch_bounds__(256) void gemm128(const float* __restrict__ X,
                                               const float* __restrict__ W,
                                               const float* __restrict__ bias,
                                               float* __restrict__ Yf,
                                               unsigned short* __restrict__ Yb,
                                               int n, int addBias) {
    __shared__ float Wl[128 * 128];
    __shared__ float Xl[TILE_ROWS * 128];
    int t = threadIdx.x;
    for (int i = t * 4; i < 128 * 128; i += 1024)
        *(float4*)&Wl[i] = *(const float4*)&W[i];
    int row0 = blockIdx.x * TILE_ROWS;
    for (int i = t * 4; i < TILE_ROWS * 128; i += 1024) {
        int r = i >> 7, c = i & 127;
        int gr = row0 + r;
        float4 v = make_float4(0.f, 0.f, 0.f, 0.f);
        if (gr < n) v = *(const float4*)&X[(size_t)gr * 128 + c];
        *(float4*)&Xl[i] = v;
    }
    __syncthreads();
    int c = t & 127;
    int rbase = (t >> 7) * 16;
    float acc[16];
#pragma unroll
    for (int i = 0; i < 16; i++) acc[i] = 0.f;
    for (int k = 0; k < 128; k += 4) {
        float w0 = Wl[(k + 0) * 128 + c];
        float w1 = Wl[(k + 1) * 128 + c];
        float w2 = Wl[(k + 2) * 128 + c];
        float w3 = Wl[(k + 3) * 128 + c];
#pragma unroll
        for (int i = 0; i < 16; i++) {
            float4 xv = *(float4*)&Xl[(rbase + i) * 128 + k];
            float a = acc[i];
            a = fmaf(xv.x, w0, a);
            a = fmaf(xv.y, w1, a);
            a = fmaf(xv.z, w2, a);
            a = fmaf(xv.w, w3, a);
            acc[i] = a;
        }
    }
    float b = addBias ? bias[c] : 0.f;
#pragma unroll
    for (int i = 0; i < 16; i++) {
        int gr = row0 + rbase + i;
        if (gr < n) {
            float o = acc[i] + b;
            if (BF16OUT) Yb[(size_t)gr * 128 + c] = f_to_bf16(o);
            else         Yf[(size_t)gr * 128 + c] = o;
        }
    }
}

// ---------------- attention coefficients (bf16 hfeat) ----------------

template <int H>
__global__ void attn_coef(const unsigned short* __restrict__ hfeat,
                          const float* __restrict__ asrc,
                          const float* __restrict__ adst, float* __restrict__ als,
                          float* __restrict__ ald, int n) {
    int idx = blockIdx.x * blockDim.x + threadIdx.x;
    if (idx >= n * H) return;
    int node = idx / H, h = idx % H;
    const int C = 128 / H;
    const unsigned int* hp =
        (const unsigned int*)(hfeat + (size_t)node * 128 + h * C);
    const float* ap = asrc + h * C;
    const float* dp = adst + h * C;
    float s = 0.f, d = 0.f;
#pragma unroll 4
    for (int c2 = 0; c2 < C / 2; c2++) {
        unsigned int u = hp[c2];
        float v0 = bf16_lo(u), v1 = bf16_hi(u);
        s = fmaf(v0, ap[2 * c2], s);
        s = fmaf(v1, ap[2 * c2 + 1], s);
        d = fmaf(v0, dp[2 * c2], d);
        d = fmaf(v1, dp[2 * c2 + 1], d);
    }
    als[idx] = s;
    ald[idx] = d;
}

// ---------------- aggregate (one wave per dst node, single pass, no max) ----
// MODE 0: out = relu(agg + bias + xskip)   (layers 1,2)
// MODE 1: out = agg + bias                 (layer 3)

template <int H, int MODE>
__global__ __launch_bounds__(256) void aggregate(const unsigned short* __restrict__ hfeat,
                                                 const float* __restrict__ als,
                                                 const float* __restrict__ ald,
                                                 const int* __restrict__ rowptr,
                                                 const int* __restrict__ col,
                                                 const float* __restrict__ bias,
                                                 const float* __restrict__ xskip,
                                                 float* __restrict__ outbuf, int n) {
    int wave = (blockIdx.x * blockDim.x + threadIdx.x) >> 6;
    int lane = threadIdx.x & 63;
    if (wave >= n) return;
    int d = wave;
    int h = (H == 4) ? (lane >> 4) : 0;
    float aldh = ald[d * H + h];
    int beg = rowptr[d], end = rowptr[d + 1];

    float ssum = 0.f, a0 = 0.f, a1 = 0.f;
    int c0 = 2 * lane;

    int i = beg;
    for (; i + 1 < end; i += 2) {
        int s0 = col[i];
        int s1 = col[i + 1];
        float v0 = als[s0 * H + h] + aldh;
        float v1 = als[s1 * H + h] + aldh;
        unsigned int u0 = *(const unsigned int*)&hfeat[(size_t)s0 * 128 + c0];
        unsigned int u1 = *(const unsigned int*)&hfeat[(size_t)s1 * 128 + c0];
        v0 = (v0 > 0.f) ? v0 : NEG_SLOPE * v0;
        v1 = (v1 > 0.f) ? v1 : NEG_SLOPE * v1;
        float p0 = __expf(fminf(v0, 60.f));
        float p1 = __expf(fminf(v1, 60.f));
        ssum += p0 + p1;
        a0 = fmaf(p0, bf16_lo(u0), a0);
        a1 = fmaf(p0, bf16_hi(u0), a1);
        a0 = fmaf(p1, bf16_lo(u1), a0);
        a1 = fmaf(p1, bf16_hi(u1), a1);
    }
    if (i < end) {
        int s0 = col[i];
        float v0 = als[s0 * H + h] + aldh;
        unsigned int u0 = *(const unsigned int*)&hfeat[(size_t)s0 * 128 + c0];
        v0 = (v0 > 0.f) ? v0 : NEG_SLOPE * v0;
        float p0 = __expf(fminf(v0, 60.f));
        ssum += p0;
        a0 = fmaf(p0, bf16_lo(u0), a0);
        a1 = fmaf(p0, bf16_hi(u0), a1);
    }

    float inv = 1.f / ssum;
    float o0 = a0 * inv + bias[c0];
    float o1 = a1 * inv + bias[c0 + 1];
    if (MODE == 0) {
        o0 = fmaxf(o0 + xskip[(size_t)d * 128 + c0], 0.f);
        o1 = fmaxf(o1 + xskip[(size_t)d * 128 + c0 + 1], 0.f);
    }
    outbuf[(size_t)d * 128 + c0] = o0;
    outbuf[(size_t)d * 128 + c0 + 1] = o1;
}

// ---------------- pooling ----------------

__global__ void pool_sum(const float* __restrict__ h, const int* __restrict__ batch,
                         float* __restrict__ ctx, float* __restrict__ cnt, int n) {
    int c = threadIdx.x;  // 0..127
    int base = blockIdx.x * 128;
    int lim = min(base + 128, n);
    float acc = 0.f, cl = 0.f;
    int curg = -1;
    for (int node = base; node < lim; node++) {
        int g = batch[node];
        if (g != curg) {
            if (curg >= 0) {
                atomicAdd(&ctx[curg * 128 + c], acc);
                if (c == 0) atomicAdd(&cnt[curg], cl);
            }
            curg = g; acc = 0.f; cl = 0.f;
        }
        acc += h[(size_t)node * 128 + c];
        cl += 1.f;
    }
    if (curg >= 0) {
        atomicAdd(&ctx[curg * 128 + c], acc);
        if (c == 0) atomicAdd(&cnt[curg], cl);
    }
}

__global__ void pool_div(float* __restrict__ ctx, const float* __restrict__ cnt) {
    int i = blockIdx.x * blockDim.x + threadIdx.x;
    if (i >= G_GROUPS * 128) return;
    int g = i >> 7;
    ctx[i] = ctx[i] / fmaxf(cnt[g], 1.f);
}

// ---------------- host ----------------

extern "C" void kernel_launch(void* const* d_in, const int* in_sizes, int n_in,
                              void* d_out, int out_size, void* d_ws, size_t ws_size,
                              hipStream_t stream) {
    const float* x   = (const float*)d_in[0];
    const int*   ei  = (const int*)d_in[1];
    const int*   bat = (const int*)d_in[2];
    const float* Wp  = (const float*)d_in[3];
    const float* bp  = (const float*)d_in[4];
    const float* W1  = (const float*)d_in[5];
    const float* as1 = (const float*)d_in[6];
    const float* ad1 = (const float*)d_in[7];
    const float* b1  = (const float*)d_in[8];
    const float* W2  = (const float*)d_in[9];
    const float* as2 = (const float*)d_in[10];
    const float* ad2 = (const float*)d_in[11];
    const float* b2  = (const float*)d_in[12];
    const float* W3  = (const float*)d_in[13];
    const float* as3 = (const float*)d_in[14];
    const float* ad3 = (const float*)d_in[15];
    const float* b3  = (const float*)d_in[16];

    float* out_h   = (float*)d_out;
    float* out_ctx = out_h + (size_t)N_NODES * 128;

    char* w = (char*)d_ws;
    float* xskip = (float*)w;          w += (size_t)N_NODES * 128 * 4;
    unsigned short* hfeat = (unsigned short*)w;  w += (size_t)N_NODES * 128 * 2;
    float* hcur  = (float*)w;          w += (size_t)N_NODES * 128 * 4;
    float* als   = (float*)w;          w += (size_t)N_NODES * 4 * 4;
    float* ald   = (float*)w;          w += (size_t)N_NODES * 4 * 4;
    float* cnt   = (float*)w;          w += 256 * 4;
    int* deg     = (int*)w;            w += (size_t)N_NODES * 4;
    int* rowptr  = (int*)w;            w += (size_t)(N_NODES + 4) * 4;
    int* cursor  = (int*)w;            w += (size_t)N_NODES * 4;
    int* bsums   = (int*)w;            w += 256 * 4;
    int* col     = (int*)w;            w += (size_t)ET_EDGES * 4;

    // zero accumulators
    hipMemsetAsync(deg, 0, N_NODES * 4, stream);
    hipMemsetAsync(cursor, 0, N_NODES * 4, stream);
    hipMemsetAsync(cnt, 0, 256 * 4, stream);
    hipMemsetAsync(out_ctx, 0, G_GROUPS * 128 * 4, stream);

    const int NB = (N_NODES + 255) / 256;
    const int EB = (ET_EDGES + 255) / 256;

    // CSR build
    count_edges<<<EB, 256, 0, stream>>>(ei, deg);
    scan_block<<<NB, 256, 0, stream>>>(deg, rowptr, bsums, N_NODES);
    scan_bsums<<<1, 256, 0, stream>>>(bsums, NB);
    scan_add<<<NB, 256, 0, stream>>>(rowptr, bsums, N_NODES);
    fill_edges<<<EB, 256, 0, stream>>>(ei, rowptr, cursor, col);

    const int GB = (N_NODES + TILE_ROWS - 1) / TILE_ROWS;
    const int AB4 = (N_NODES * 4 + 255) / 256;
    const int AB1 = (N_NODES + 255) / 256;
    const int AGB = (N_NODES * 64 + 255) / 256;

    // x_skip = x @ Wp + bp  (fp32 out)
    gemm128<0><<<GB, 256, 0, stream>>>(x, Wp, bp, xskip, nullptr, N_NODES, 1);

    // layer 1
    gemm128<1><<<GB, 256, 0, stream>>>(x, W1, nullptr, nullptr, hfeat, N_NODES, 0);
    attn_coef<4><<<AB4, 256, 0, stream>>>(hfeat, as1, ad1, als, ald, N_NODES);
    aggregate<4, 0><<<AGB, 256, 0, stream>>>(hfeat, als, ald, rowptr, col, b1, xskip, hcur, N_NODES);

    // layer 2
    gemm128<1><<<GB, 256, 0, stream>>>(hcur, W2, nullptr, nullptr, hfeat, N_NODES, 0);
    attn_coef<4><<<AB4, 256, 0, stream>>>(hfeat, as2, ad2, als, ald, N_NODES);
    aggregate<4, 0><<<AGB, 256, 0, stream>>>(hfeat, als, ald, rowptr, col, b2, xskip, hcur, N_NODES);

    // layer 3 (heads=1, no skip/relu) -> d_out
    gemm128<1><<<GB, 256, 0, stream>>>(hcur, W3, nullptr, nullptr, hfeat, N_NODES, 0);
    attn_coef<1><<<AB1, 256, 0, stream>>>(hfeat, as3, ad3, als, ald, N_NODES);
    aggregate<1, 1><<<AGB, 256, 0, stream>>>(hfeat, als, ald, rowptr, col, b3, nullptr, out_h, N_NODES);

    // global mean pool
    pool_sum<<<(N_NODES + 127) / 128, 128, 0, stream>>>(out_h, bat, out_ctx, cnt, N_NODES);
    pool_div<<<(G_GROUPS * 128 + 255) / 256, 256, 0, stream>>>(out_ctx, cnt);
}

// Round 4
// 410.446 us; speedup vs baseline: 2.0721x; 1.4579x over previous
//
#include <hip/hip_runtime.h>
#include <hip/hip_bf16.h>
#include <math.h>

#define N_NODES 50000
#define N_EDGES 800000
#define ET_EDGES (N_EDGES + N_NODES)
#define G_GROUPS 64
#define NEG_SLOPE 0.2f

typedef __attribute__((ext_vector_type(8))) short bf16x8;
typedef __attribute__((ext_vector_type(4))) float f32x4;

static __device__ __forceinline__ float bf16_lo(unsigned int u) {
    return __uint_as_float(u << 16);
}
static __device__ __forceinline__ float bf16_hi(unsigned int u) {
    return __uint_as_float(u & 0xffff0000u);
}
static __device__ __forceinline__ unsigned short f_to_bf16(float f) {
    unsigned int u = __float_as_uint(f);
    unsigned int r = (u + 0x7fffu + ((u >> 16) & 1u)) >> 16;  // RNE
    return (unsigned short)r;
}

// ---------------- converts ----------------

__global__ void convert_x(const float* __restrict__ x, unsigned short* __restrict__ xb,
                          int total8) {
    int i = blockIdx.x * blockDim.x + threadIdx.x;
    if (i >= total8) return;
    const float4* p = (const float4*)(x + (size_t)i * 8);
    float4 v0 = p[0], v1 = p[1];
    ushort4 o0, o1;
    o0.x = f_to_bf16(v0.x); o0.y = f_to_bf16(v0.y);
    o0.z = f_to_bf16(v0.z); o0.w = f_to_bf16(v0.w);
    o1.x = f_to_bf16(v1.x); o1.y = f_to_bf16(v1.y);
    o1.z = f_to_bf16(v1.z); o1.w = f_to_bf16(v1.w);
    ushort4* q = (ushort4*)(xb + (size_t)i * 8);
    q[0] = o0; q[1] = o1;
}

// Wt[c*128+k] = bf16(W[k*128+c]) for 4 matrices
__global__ void convert_w(const float* __restrict__ W0, const float* __restrict__ W1,
                          const float* __restrict__ W2, const float* __restrict__ W3,
                          unsigned short* __restrict__ T0, unsigned short* __restrict__ T1,
                          unsigned short* __restrict__ T2, unsigned short* __restrict__ T3) {
    int tid = blockIdx.x * blockDim.x + threadIdx.x;  // 0..65535
    int m = tid >> 14;
    int idx = tid & 16383;       // source index k*128+c (coalesced read)
    int k = idx >> 7, c = idx & 127;
    const float* W = (m == 0) ? W0 : (m == 1) ? W1 : (m == 2) ? W2 : W3;
    unsigned short* T = (m == 0) ? T0 : (m == 1) ? T1 : (m == 2) ? T2 : T3;
    T[c * 128 + k] = f_to_bf16(W[idx]);
}

// ---------------- CSR build ----------------

__global__ void count_edges(const int* __restrict__ ei, int* __restrict__ deg) {
    int e = blockIdx.x * blockDim.x + threadIdx.x;
    if (e >= ET_EDGES) return;
    int dst = (e < N_EDGES) ? ei[N_EDGES + e] : (e - N_EDGES);
    atomicAdd(&deg[dst], 1);
}

__global__ void scan_block(const int* __restrict__ deg, int* __restrict__ rowptr,
                           int* __restrict__ bsums, int n) {
    __shared__ int sd[256];
    int i = blockIdx.x * 256 + threadIdx.x;
    int v = (i < n) ? deg[i] : 0;
    sd[threadIdx.x] = v;
    __syncthreads();
    for (int off = 1; off < 256; off <<= 1) {
        int t = (threadIdx.x >= off) ? sd[threadIdx.x - off] : 0;
        __syncthreads();
        sd[threadIdx.x] += t;
        __syncthreads();
    }
    if (i < n) rowptr[i] = sd[threadIdx.x] - v;
    if (threadIdx.x == 255) bsums[blockIdx.x] = sd[255];
}

__global__ void scan_bsums(int* __restrict__ bsums, int nb) {
    __shared__ int sd[256];
    int v = (threadIdx.x < nb) ? bsums[threadIdx.x] : 0;
    sd[threadIdx.x] = v;
    __syncthreads();
    for (int off = 1; off < 256; off <<= 1) {
        int t = (threadIdx.x >= off) ? sd[threadIdx.x - off] : 0;
        __syncthreads();
        sd[threadIdx.x] += t;
        __syncthreads();
    }
    if (threadIdx.x < nb) bsums[threadIdx.x] = sd[threadIdx.x] - v;
}

__global__ void scan_add(int* __restrict__ rowptr, const int* __restrict__ bsums, int n) {
    int i = blockIdx.x * 256 + threadIdx.x;
    if (i < n) rowptr[i] += bsums[blockIdx.x];
    if (i == 0) rowptr[n] = ET_EDGES;
}

__global__ void fill_edges(const int* __restrict__ ei, const int* __restrict__ rowptr,
                           int* __restrict__ cursor, int* __restrict__ col) {
    int e = blockIdx.x * blockDim.x + threadIdx.x;
    if (e >= ET_EDGES) return;
    int src, dst;
    if (e < N_EDGES) { src = ei[e]; dst = ei[N_EDGES + e]; }
    else             { src = e - N_EDGES; dst = src; }
    int pos = rowptr[dst] + atomicAdd(&cursor[dst], 1);
    col[pos] = src;
}

// ---------------- MFMA GEMM: Y[n,128] = Xb[n,128] @ W[128,128] ----------------
// Xb bf16 row-major; Wt bf16 [c][k] (transposed W). 64 rows/block, 4 waves.

__global__ __launch_bounds__(256) void gemm_mfma(const unsigned short* __restrict__ Xb,
                                                 const unsigned short* __restrict__ Wt,
                                                 const float* __restrict__ bias,
                                                 float* __restrict__ Yf,
                                                 unsigned short* __restrict__ Yb,
                                                 int n, int addBias, int bf16out) {
    __shared__ unsigned short Wl[128 * 128];
    char* wl = (char*)Wl;
    int t = threadIdx.x;
    // stage W^T (32KB) with XOR swizzle: byte_off_in_row ^= (row&7)<<4
#pragma unroll
    for (int i = 0; i < 8; i++) {
        int slot = i * 256 + t;          // uint4 slots 0..2047
        int byte = slot * 16;
        int r = byte >> 8;
        int off = byte & 255;
        uint4 v = *(const uint4*)((const char*)Wt + byte);
        *(uint4*)(wl + r * 256 + (off ^ ((r & 7) << 4))) = v;
    }
    __syncthreads();

    int wave = t >> 6, lane = t & 63;
    int lr = lane & 15, lk = lane >> 4;  // lk 0..3
    int arow = blockIdx.x * 64 + wave * 16 + lr;
    int arowc = min(arow, n - 1);
    const char* xrow = (const char*)(Xb + (size_t)arowc * 128);
    bf16x8 a[4];
#pragma unroll
    for (int ks = 0; ks < 4; ks++)
        a[ks] = *(const bf16x8*)(xrow + ks * 64 + lk * 16);

    f32x4 zero = {0.f, 0.f, 0.f, 0.f};
    f32x4 acc[8];
#pragma unroll
    for (int j = 0; j < 8; j++) acc[j] = zero;

#pragma unroll
    for (int j = 0; j < 8; j++) {
        int c = j * 16 + lr;
        const char* wrow = wl + c * 256;
        int sw = (c & 7) << 4;
#pragma unroll
        for (int ks = 0; ks < 4; ks++) {
            bf16x8 b = *(const bf16x8*)(wrow + ((ks * 64 + lk * 16) ^ sw));
            acc[j] = __builtin_amdgcn_mfma_f32_16x16x32_bf16(a[ks], b, acc[j], 0, 0, 0);
        }
    }

    int orow0 = blockIdx.x * 64 + wave * 16 + lk * 4;
#pragma unroll
    for (int j = 0; j < 8; j++) {
        int c = j * 16 + lr;
        float bv = addBias ? bias[c] : 0.f;
#pragma unroll
        for (int r = 0; r < 4; r++) {
            int orow = orow0 + r;
            if (orow < n) {
                float o = acc[j][r] + bv;
                if (bf16out) Yb[(size_t)orow * 128 + c] = f_to_bf16(o);
                else         Yf[(size_t)orow * 128 + c] = o;
            }
        }
    }
}

// ---------------- attention coefficients (bf16 hfeat) ----------------

template <int H>
__global__ void attn_coef(const unsigned short* __restrict__ hfeat,
                          const float* __restrict__ asrc,
                          const float* __restrict__ adst, float* __restrict__ als,
                          float* __restrict__ ald, int n) {
    int idx = blockIdx.x * blockDim.x + threadIdx.x;
    if (idx >= n * H) return;
    int node = idx / H, h = idx % H;
    const int C = 128 / H;
    const unsigned int* hp =
        (const unsigned int*)(hfeat + (size_t)node * 128 + h * C);
    const float* ap = asrc + h * C;
    const float* dp = adst + h * C;
    float s = 0.f, d = 0.f;
#pragma unroll 4
    for (int c2 = 0; c2 < C / 2; c2++) {
        unsigned int u = hp[c2];
        float v0 = bf16_lo(u), v1 = bf16_hi(u);
        s = fmaf(v0, ap[2 * c2], s);
        s = fmaf(v1, ap[2 * c2 + 1], s);
        d = fmaf(v0, dp[2 * c2], d);
        d = fmaf(v1, dp[2 * c2 + 1], d);
    }
    als[idx] = s;
    ald[idx] = d;
}

// ---------------- aggregate (one wave per dst node, single pass) ----------
// MODE 0: hcur_bf16 = relu(agg + bias + xskip)   (layers 1,2)
// MODE 1: out_f32   = agg + bias                 (layer 3)

template <int H, int MODE>
__global__ __launch_bounds__(256) void aggregate(const unsigned short* __restrict__ hfeat,
                                                 const float* __restrict__ als,
                                                 const float* __restrict__ ald,
                                                 const int* __restrict__ rowptr,
                                                 const int* __restrict__ col,
                                                 const float* __restrict__ bias,
                                                 const float* __restrict__ xskip,
                                                 float* __restrict__ outf,
                                                 unsigned short* __restrict__ outb, int n) {
    int wave = (blockIdx.x * blockDim.x + threadIdx.x) >> 6;
    int lane = threadIdx.x & 63;
    if (wave >= n) return;
    int d = wave;
    int h = (H == 4) ? (lane >> 4) : 0;
    float aldh = ald[d * H + h];
    int beg = rowptr[d], end = rowptr[d + 1];

    float ssum = 0.f, a0 = 0.f, a1 = 0.f;
    int c0 = 2 * lane;

    int i = beg;
    for (; i + 1 < end; i += 2) {
        int s0 = col[i];
        int s1 = col[i + 1];
        float v0 = als[s0 * H + h] + aldh;
        float v1 = als[s1 * H + h] + aldh;
        unsigned int u0 = *(const unsigned int*)&hfeat[(size_t)s0 * 128 + c0];
        unsigned int u1 = *(const unsigned int*)&hfeat[(size_t)s1 * 128 + c0];
        v0 = (v0 > 0.f) ? v0 : NEG_SLOPE * v0;
        v1 = (v1 > 0.f) ? v1 : NEG_SLOPE * v1;
        float p0 = __expf(fminf(v0, 60.f));
        float p1 = __expf(fminf(v1, 60.f));
        ssum += p0 + p1;
        a0 = fmaf(p0, bf16_lo(u0), a0);
        a1 = fmaf(p0, bf16_hi(u0), a1);
        a0 = fmaf(p1, bf16_lo(u1), a0);
        a1 = fmaf(p1, bf16_hi(u1), a1);
    }
    if (i < end) {
        int s0 = col[i];
        float v0 = als[s0 * H + h] + aldh;
        unsigned int u0 = *(const unsigned int*)&hfeat[(size_t)s0 * 128 + c0];
        v0 = (v0 > 0.f) ? v0 : NEG_SLOPE * v0;
        float p0 = __expf(fminf(v0, 60.f));
        ssum += p0;
        a0 = fmaf(p0, bf16_lo(u0), a0);
        a1 = fmaf(p0, bf16_hi(u0), a1);
    }

    float inv = 1.f / ssum;
    float o0 = a0 * inv + bias[c0];
    float o1 = a1 * inv + bias[c0 + 1];
    if (MODE == 0) {
        o0 = fmaxf(o0 + xskip[(size_t)d * 128 + c0], 0.f);
        o1 = fmaxf(o1 + xskip[(size_t)d * 128 + c0 + 1], 0.f);
        unsigned int packed = (unsigned int)f_to_bf16(o0) |
                              ((unsigned int)f_to_bf16(o1) << 16);
        *(unsigned int*)&outb[(size_t)d * 128 + c0] = packed;
    } else {
        outf[(size_t)d * 128 + c0] = o0;
        outf[(size_t)d * 128 + c0 + 1] = o1;
    }
}

// ---------------- pooling ----------------

__global__ void pool_sum(const float* __restrict__ h, const int* __restrict__ batch,
                         float* __restrict__ ctx, float* __restrict__ cnt, int n) {
    int c = threadIdx.x;
    int base = blockIdx.x * 128;
    int lim = min(base + 128, n);
    float acc = 0.f, cl = 0.f;
    int curg = -1;
    for (int node = base; node < lim; node++) {
        int g = batch[node];
        if (g != curg) {
            if (curg >= 0) {
                atomicAdd(&ctx[curg * 128 + c], acc);
                if (c == 0) atomicAdd(&cnt[curg], cl);
            }
            curg = g; acc = 0.f; cl = 0.f;
        }
        acc += h[(size_t)node * 128 + c];
        cl += 1.f;
    }
    if (curg >= 0) {
        atomicAdd(&ctx[curg * 128 + c], acc);
        if (c == 0) atomicAdd(&cnt[curg], cl);
    }
}

__global__ void pool_div(float* __restrict__ ctx, const float* __restrict__ cnt) {
    int i = blockIdx.x * blockDim.x + threadIdx.x;
    if (i >= G_GROUPS * 128) return;
    int g = i >> 7;
    ctx[i] = ctx[i] / fmaxf(cnt[g], 1.f);
}

// ---------------- host ----------------

extern "C" void kernel_launch(void* const* d_in, const int* in_sizes, int n_in,
                              void* d_out, int out_size, void* d_ws, size_t ws_size,
                              hipStream_t stream) {
    const float* x   = (const float*)d_in[0];
    const int*   ei  = (const int*)d_in[1];
    const int*   bat = (const int*)d_in[2];
    const float* Wp  = (const float*)d_in[3];
    const float* bp  = (const float*)d_in[4];
    const float* W1  = (const float*)d_in[5];
    const float* as1 = (const float*)d_in[6];
    const float* ad1 = (const float*)d_in[7];
    const float* b1  = (const float*)d_in[8];
    const float* W2  = (const float*)d_in[9];
    const float* as2 = (const float*)d_in[10];
    const float* ad2 = (const float*)d_in[11];
    const float* b2  = (const float*)d_in[12];
    const float* W3  = (const float*)d_in[13];
    const float* as3 = (const float*)d_in[14];
    const float* ad3 = (const float*)d_in[15];
    const float* b3  = (const float*)d_in[16];

    float* out_h   = (float*)d_out;
    float* out_ctx = out_h + (size_t)N_NODES * 128;

    char* w = (char*)d_ws;
    float* xskip = (float*)w;                    w += (size_t)N_NODES * 128 * 4;
    unsigned short* hfeat = (unsigned short*)w;  w += (size_t)N_NODES * 128 * 2;
    unsigned short* hcur  = (unsigned short*)w;  w += (size_t)N_NODES * 128 * 2;
    unsigned short* xb    = (unsigned short*)w;  w += (size_t)N_NODES * 128 * 2;
    unsigned short* Wtp   = (unsigned short*)w;  w += 16384 * 2;
    unsigned short* Wt1   = (unsigned short*)w;  w += 16384 * 2;
    unsigned short* Wt2   = (unsigned short*)w;  w += 16384 * 2;
    unsigned short* Wt3   = (unsigned short*)w;  w += 16384 * 2;
    float* als   = (float*)w;                    w += (size_t)N_NODES * 4 * 4;
    float* ald   = (float*)w;                    w += (size_t)N_NODES * 4 * 4;
    float* cnt   = (float*)w;                    w += 256 * 4;
    int* deg     = (int*)w;                      w += (size_t)N_NODES * 4;
    int* rowptr  = (int*)w;                      w += (size_t)(N_NODES + 4) * 4;
    int* cursor  = (int*)w;                      w += (size_t)N_NODES * 4;
    int* bsums   = (int*)w;                      w += 256 * 4;
    int* col     = (int*)w;                      w += (size_t)ET_EDGES * 4;

    hipMemsetAsync(deg, 0, N_NODES * 4, stream);
    hipMemsetAsync(cursor, 0, N_NODES * 4, stream);
    hipMemsetAsync(cnt, 0, 256 * 4, stream);
    hipMemsetAsync(out_ctx, 0, G_GROUPS * 128 * 4, stream);

    const int NB = (N_NODES + 255) / 256;
    const int EB = (ET_EDGES + 255) / 256;

    // converts
    convert_w<<<256, 256, 0, stream>>>(Wp, W1, W2, W3, Wtp, Wt1, Wt2, Wt3);
    {
        int total8 = N_NODES * 16;  // 800000 chunks of 8 floats
        convert_x<<<(total8 + 255) / 256, 256, 0, stream>>>(x, xb, total8);
    }

    // CSR build
    count_edges<<<EB, 256, 0, stream>>>(ei, deg);
    scan_block<<<NB, 256, 0, stream>>>(deg, rowptr, bsums, N_NODES);
    scan_bsums<<<1, 256, 0, stream>>>(bsums, NB);
    scan_add<<<NB, 256, 0, stream>>>(rowptr, bsums, N_NODES);
    fill_edges<<<EB, 256, 0, stream>>>(ei, rowptr, cursor, col);

    const int GB = (N_NODES + 63) / 64;  // 782
    const int AB4 = (N_NODES * 4 + 255) / 256;
    const int AB1 = (N_NODES + 255) / 256;
    const int AGB = (N_NODES * 64 + 255) / 256;

    // x_skip = x @ Wp + bp  (fp32 out)
    gemm_mfma<<<GB, 256, 0, stream>>>(xb, Wtp, bp, xskip, nullptr, N_NODES, 1, 0);

    // layer 1
    gemm_mfma<<<GB, 256, 0, stream>>>(xb, Wt1, nullptr, nullptr, hfeat, N_NODES, 0, 1);
    attn_coef<4><<<AB4, 256, 0, stream>>>(hfeat, as1, ad1, als, ald, N_NODES);
    aggregate<4, 0><<<AGB, 256, 0, stream>>>(hfeat, als, ald, rowptr, col, b1, xskip,
                                             nullptr, hcur, N_NODES);

    // layer 2
    gemm_mfma<<<GB, 256, 0, stream>>>(hcur, Wt2, nullptr, nullptr, hfeat, N_NODES, 0, 1);
    attn_coef<4><<<AB4, 256, 0, stream>>>(hfeat, as2, ad2, als, ald, N_NODES);
    aggregate<4, 0><<<AGB, 256, 0, stream>>>(hfeat, als, ald, rowptr, col, b2, xskip,
                                             nullptr, hcur, N_NODES);

    // layer 3 (heads=1) -> d_out
    gemm_mfma<<<GB, 256, 0, stream>>>(hcur, Wt3, nullptr, nullptr, hfeat, N_NODES, 0, 1);
    attn_coef<1><<<AB1, 256, 0, stream>>>(hfeat, as3, ad3, als, ald, N_NODES);
    aggregate<1, 1><<<AGB, 256, 0, stream>>>(hfeat, als, ald, rowptr, col, b3, nullptr,
                                             out_h, nullptr, N_NODES);

    // global mean pool
    pool_sum<<<(N_NODES + 127) / 128, 128, 0, stream>>>(out_h, bat, out_ctx, cnt, N_NODES);
    pool_div<<<(G_GROUPS * 128 + 255) / 256, 256, 0, stream>>>(out_ctx, cnt);
}